// Round 1
// baseline (613.621 us; speedup 1.0000x reference)
//
#include <hip/hip_runtime.h>

// GraphSAGE 2-layer, fp32, D=64.
// N0=900000, N1=43008, N2=2048, FANOUT=20.
// Stage 1: scatter-mean of x over edges0 -> sum0/cnt0 (atomics)
// Stage 2: h = relu(concat(x[:N1], sum0/cnt) @ w0 + b0)
// Stage 3: scatter-mean of h over edges1 -> sum1/cnt1
// Stage 4: out = concat(h[:N2], sum1/cnt) @ w1 + b1

#define D 64
constexpr int N1c = 43008;
constexpr int N2c = 2048;

// One wave (64 lanes) per edge: lane d handles feature d.
// Edge index is wave-uniform -> broadcast loads; row read/atomic coalesced.
__global__ void scatter_kernel(const float* __restrict__ feat,
                               const int* __restrict__ src,
                               const int* __restrict__ dst,
                               float* __restrict__ sums,
                               float* __restrict__ cnt,
                               int nedges) {
    long long tid = (long long)blockIdx.x * blockDim.x + threadIdx.x;
    int e = (int)(tid >> 6);
    int d = (int)(tid & 63);
    if (e >= nedges) return;
    int s = src[e];
    int t = dst[e];
    atomicAdd(&sums[(size_t)t * D + d], feat[(size_t)s * D + d]);
    if (d == 0) atomicAdd(&cnt[t], 1.0f);
}

// One thread per output element (row i, col j). Wave shares row i.
__global__ void dense_kernel(const float* __restrict__ self_feat,
                             const float* __restrict__ sums,
                             const float* __restrict__ cnt,
                             const float* __restrict__ w,   // [2D, D] row-major
                             const float* __restrict__ b,   // [D]
                             float* __restrict__ out,
                             int nrows, int do_relu) {
    long long tid = (long long)blockIdx.x * blockDim.x + threadIdx.x;
    int i = (int)(tid >> 6);
    int j = (int)(tid & 63);
    if (i >= nrows) return;
    float inv = 1.0f / fmaxf(cnt[i], 1.0f);
    float acc = b[j];
    const float* xr = self_feat + (size_t)i * D;
    const float* sr = sums + (size_t)i * D;
#pragma unroll 8
    for (int k = 0; k < D; ++k)
        acc += xr[k] * w[k * D + j];
#pragma unroll 8
    for (int k = 0; k < D; ++k)
        acc += (sr[k] * inv) * w[(D + k) * D + j];
    if (do_relu) acc = fmaxf(acc, 0.0f);
    out[(size_t)i * D + j] = acc;
}

extern "C" void kernel_launch(void* const* d_in, const int* in_sizes, int n_in,
                              void* d_out, int out_size, void* d_ws, size_t ws_size,
                              hipStream_t stream) {
    const float* x   = (const float*)d_in[0];
    const float* w0  = (const float*)d_in[1];
    const float* b0  = (const float*)d_in[2];
    const float* w1  = (const float*)d_in[3];
    const float* b1  = (const float*)d_in[4];
    const int* es0   = (const int*)d_in[5];
    const int* ed0   = (const int*)d_in[6];
    const int* es1   = (const int*)d_in[7];
    const int* ed1   = (const int*)d_in[8];
    const int E0 = in_sizes[5];
    const int E1 = in_sizes[7];

    // Workspace layout (floats): sum0 | cnt0 | sum1 | cnt1 | h
    float* sum0 = (float*)d_ws;
    float* cnt0 = sum0 + (size_t)N1c * D;
    float* sum1 = cnt0 + N1c;
    float* cnt1 = sum1 + (size_t)N2c * D;
    float* h    = cnt1 + N2c;

    // Zero the accumulator region (sum0..cnt1 contiguous). h is fully written.
    size_t zero_bytes = ((size_t)N1c * D + N1c + (size_t)N2c * D + N2c) * sizeof(float);
    hipMemsetAsync(d_ws, 0, zero_bytes, stream);

    {   // L0 scatter: one wave per edge
        long long threads = (long long)E0 * 64;
        int blocks = (int)((threads + 255) / 256);
        scatter_kernel<<<blocks, 256, 0, stream>>>(x, es0, ed0, sum0, cnt0, E0);
    }
    {   // L0 linear + relu -> h [N1, D]
        int blocks = (N1c * 64 + 255) / 256;
        dense_kernel<<<blocks, 256, 0, stream>>>(x, sum0, cnt0, w0, b0, h, N1c, 1);
    }
    {   // L1 scatter
        long long threads = (long long)E1 * 64;
        int blocks = (int)((threads + 255) / 256);
        scatter_kernel<<<blocks, 256, 0, stream>>>(h, es1, ed1, sum1, cnt1, E1);
    }
    {   // L1 linear -> out [N2, D]
        int blocks = (N2c * 64 + 255) / 256;
        dense_kernel<<<blocks, 256, 0, stream>>>(h, sum1, cnt1, w1, b1, (float*)d_out, N2c, 0);
    }
}

// Round 2
// 559.610 us; speedup vs baseline: 1.0965x; 1.0965x over previous
//
#include <hip/hip_runtime.h>

// GraphSAGE 2-layer, fp32, D=64. N0=900000, N1=43008, N2=2048, FANOUT=20.
//
// Round 2: de-atomicized layer 0. Build CSR (dst -> srcs) per call:
//   hist -> segment sums -> block scan -> wave scan -> fill (int atomics only)
// then ONE fused kernel per target row (wave): gather+mean in registers,
// dense (concat @ w0 + b0, relu) with w0 in LDS, readlane broadcasts.
// Layer 1 (40960 edges) keeps the cheap atomic path.

#define D 64
constexpr int N1c = 43008;          // = 672 * 64 exactly
constexpr int N2c = 2048;
constexpr int SEGS = N1c / 64;      // 672

static __device__ __forceinline__ float readlane_f(float v, int l) {
    return __builtin_bit_cast(float, __builtin_amdgcn_readlane(__builtin_bit_cast(int, v), l));
}

// ---- CSR build ----
__global__ void hist_kernel(const int* __restrict__ dst, int* __restrict__ deg, int nedges) {
    int e = blockIdx.x * blockDim.x + threadIdx.x;
    if (e < nedges) atomicAdd(&deg[dst[e]], 1);
}

// one wave per 64-entry segment: segment sum
__global__ void segsum_kernel(const int* __restrict__ deg, int* __restrict__ segsum) {
    int w = (blockIdx.x * blockDim.x + threadIdx.x) >> 6;
    int lane = threadIdx.x & 63;
    if (w >= SEGS) return;
    int v = deg[w * 64 + lane];
    for (int off = 32; off > 0; off >>= 1) v += __shfl_down(v, off, 64);
    if (lane == 0) segsum[w] = v;
}

// single 1024-thread block: exclusive scan of SEGS segment sums
__global__ void scanblk_kernel(const int* __restrict__ segsum, int* __restrict__ segoff) {
    __shared__ int s[1024];
    int tid = threadIdx.x;
    int orig = (tid < SEGS) ? segsum[tid] : 0;
    s[tid] = orig;
    __syncthreads();
    for (int off = 1; off < 1024; off <<= 1) {
        int v = s[tid];
        int t = (tid >= off) ? s[tid - off] : 0;
        __syncthreads();
        s[tid] = v + t;
        __syncthreads();
    }
    if (tid < SEGS) segoff[tid] = s[tid] - orig;   // exclusive
}

// one wave per segment: exclusive scan within segment + segment offset
__global__ void scanwave_kernel(const int* __restrict__ deg, const int* __restrict__ segoff,
                                int* __restrict__ offsets, int* __restrict__ cursor) {
    int w = (blockIdx.x * blockDim.x + threadIdx.x) >> 6;
    int lane = threadIdx.x & 63;
    if (w >= SEGS) return;
    int i = w * 64 + lane;
    int d = deg[i];
    int v = d;
    for (int off = 1; off < 64; off <<= 1) {
        int t = __shfl_up(v, off, 64);
        if (lane >= off) v += t;
    }
    int pos = segoff[w] + v - d;   // exclusive
    offsets[i] = pos;
    cursor[i] = pos;
}

__global__ void fill_kernel(const int* __restrict__ src, const int* __restrict__ dst,
                            int* __restrict__ cursor, int* __restrict__ bucket, int nedges) {
    int e = blockIdx.x * blockDim.x + threadIdx.x;
    if (e < nedges) {
        int pos = atomicAdd(&cursor[dst[e]], 1);
        bucket[pos] = src[e];
    }
}

// ---- fused aggregate + dense + relu for layer 0 ----
// one wave per target row; 4 waves / 256-thread block; w0 staged in LDS.
__global__ void __launch_bounds__(256)
fused0_kernel(const float* __restrict__ x,
              const int* __restrict__ offsets, const int* __restrict__ deg,
              const int* __restrict__ bucket,
              const float* __restrict__ w0, const float* __restrict__ b0,
              float* __restrict__ h) {
    __shared__ float wlds[2 * D * D];   // 8192 floats = 32 KB
    int tid = threadIdx.x;
#pragma unroll
    for (int t = 0; t < 32; ++t)
        wlds[t * 256 + tid] = w0[t * 256 + tid];
    __syncthreads();

    int i = blockIdx.x * 4 + (tid >> 6);
    int lane = tid & 63;
    if (i >= N1c) return;

    int off = offsets[i];
    int dg  = deg[i];

    // gather + sum: lane holds feature `lane`
    float acc = 0.0f;
    for (int base = 0; base < dg; base += 64) {
        int m = dg - base; if (m > 64) m = 64;
        int sidx = (lane < m) ? bucket[off + base + lane] : 0;
        for (int t = 0; t < m; ++t) {
            int s = __builtin_amdgcn_readlane(sidx, t);
            acc += x[(size_t)s * D + lane];
        }
    }
    float inv = 1.0f / fmaxf((float)dg, 1.0f);
    float ag = acc * inv;                 // aggr[lane]
    float xv = x[(size_t)i * D + lane];   // x[i][lane]

    float o = b0[lane];
#pragma unroll
    for (int k = 0; k < D; ++k)
        o += readlane_f(xv, k) * wlds[k * D + lane];
#pragma unroll
    for (int k = 0; k < D; ++k)
        o += readlane_f(ag, k) * wlds[(D + k) * D + lane];

    o = fmaxf(o, 0.0f);
    h[(size_t)i * D + lane] = o;
}

// ---- layer 1: small, keep atomic scatter + simple dense ----
__global__ void scatter_kernel(const float* __restrict__ feat,
                               const int* __restrict__ src,
                               const int* __restrict__ dst,
                               float* __restrict__ sums,
                               float* __restrict__ cnt,
                               int nedges) {
    long long tid = (long long)blockIdx.x * blockDim.x + threadIdx.x;
    int e = (int)(tid >> 6);
    int d = (int)(tid & 63);
    if (e >= nedges) return;
    int s = src[e];
    int t = dst[e];
    atomicAdd(&sums[(size_t)t * D + d], feat[(size_t)s * D + d]);
    if (d == 0) atomicAdd(&cnt[t], 1.0f);
}

__global__ void dense_kernel(const float* __restrict__ self_feat,
                             const float* __restrict__ sums,
                             const float* __restrict__ cnt,
                             const float* __restrict__ w,
                             const float* __restrict__ b,
                             float* __restrict__ out,
                             int nrows, int do_relu) {
    long long tid = (long long)blockIdx.x * blockDim.x + threadIdx.x;
    int i = (int)(tid >> 6);
    int j = (int)(tid & 63);
    if (i >= nrows) return;
    float inv = 1.0f / fmaxf(cnt[i], 1.0f);
    float acc = b[j];
    const float* xr = self_feat + (size_t)i * D;
    const float* sr = sums + (size_t)i * D;
#pragma unroll 8
    for (int k = 0; k < D; ++k)
        acc += xr[k] * w[k * D + j];
#pragma unroll 8
    for (int k = 0; k < D; ++k)
        acc += (sr[k] * inv) * w[(D + k) * D + j];
    if (do_relu) acc = fmaxf(acc, 0.0f);
    out[(size_t)i * D + j] = acc;
}

extern "C" void kernel_launch(void* const* d_in, const int* in_sizes, int n_in,
                              void* d_out, int out_size, void* d_ws, size_t ws_size,
                              hipStream_t stream) {
    const float* x   = (const float*)d_in[0];
    const float* w0  = (const float*)d_in[1];
    const float* b0  = (const float*)d_in[2];
    const float* w1  = (const float*)d_in[3];
    const float* b1  = (const float*)d_in[4];
    const int* es0   = (const int*)d_in[5];
    const int* ed0   = (const int*)d_in[6];
    const int* es1   = (const int*)d_in[7];
    const int* ed1   = (const int*)d_in[8];
    const int E0 = in_sizes[5];
    const int E1 = in_sizes[7];

    // Workspace layout. [deg | sum1 | cnt1] zeroed by one memset.
    int*   deg    = (int*)d_ws;                    // N1c
    float* sum1   = (float*)(deg + N1c);           // N2c*D
    float* cnt1   = sum1 + (size_t)N2c * D;        // N2c
    int*   segsum = (int*)(cnt1 + N2c);            // SEGS
    int*   segoff = segsum + SEGS;                 // SEGS
    int*   offsets= segoff + SEGS;                 // N1c
    int*   cursor = offsets + N1c;                 // N1c
    int*   bucket = cursor + N1c;                  // E0
    float* h      = (float*)(bucket + E0);         // N1c*D

    size_t zero_bytes = ((size_t)N1c + (size_t)N2c * D + N2c) * sizeof(int);
    hipMemsetAsync(d_ws, 0, zero_bytes, stream);

    // CSR build for layer 0
    hist_kernel<<<(E0 + 255) / 256, 256, 0, stream>>>(ed0, deg, E0);
    segsum_kernel<<<(SEGS * 64 + 255) / 256, 256, 0, stream>>>(deg, segsum);
    scanblk_kernel<<<1, 1024, 0, stream>>>(segsum, segoff);
    scanwave_kernel<<<(SEGS * 64 + 255) / 256, 256, 0, stream>>>(deg, segoff, offsets, cursor);
    fill_kernel<<<(E0 + 255) / 256, 256, 0, stream>>>(es0, ed0, cursor, bucket, E0);

    // fused aggregate + dense + relu -> h
    fused0_kernel<<<N1c / 4, 256, 0, stream>>>(x, offsets, deg, bucket, w0, b0, h);

    // layer 1
    {
        long long threads = (long long)E1 * 64;
        int blocks = (int)((threads + 255) / 256);
        scatter_kernel<<<blocks, 256, 0, stream>>>(h, es1, ed1, sum1, cnt1, E1);
    }
    dense_kernel<<<(N2c * 64 + 255) / 256, 256, 0, stream>>>(h, sum1, cnt1, w1, b1,
                                                             (float*)d_out, N2c, 0);
}

// Round 3
// 490.867 us; speedup vs baseline: 1.2501x; 1.1400x over previous
//
#include <hip/hip_runtime.h>

// GraphSAGE 2-layer, fp32, D=64. N0=900000, N1=43008, N2=2048, FANOUT=20.
//
// Round 3: split aggregate/dense for layer 0.
//   aggr0: wave per row, 8 independent neighbor loads in flight (8 accs),
//          tail masked via cndmask on index-0 row (L1-hot). No LDS.
//   dense0: 4 rows per wave, w0 staged in LDS (32KB), readlane broadcasts
//          -> 32 LDS reads/row instead of 128.
//   CSR build: hist -> single-block scan -> fill.
// Layer 1 (small) keeps atomic scatter + simple dense.

#define D 64
constexpr int N1c = 43008;          // = 1024 * 42
constexpr int N2c = 2048;

static __device__ __forceinline__ float readlane_f(float v, int l) {
    return __builtin_bit_cast(float, __builtin_amdgcn_readlane(__builtin_bit_cast(int, v), l));
}

// ---- CSR build ----
__global__ void hist_kernel(const int* __restrict__ dst, int* __restrict__ deg, int nedges) {
    int e = blockIdx.x * blockDim.x + threadIdx.x;
    if (e < nedges) atomicAdd(&deg[dst[e]], 1);
}

// single 1024-thread block: exclusive scan of all N1c degrees (42 per thread)
__global__ void scan_kernel(const int* __restrict__ deg,
                            int* __restrict__ offsets, int* __restrict__ cursor) {
    __shared__ int s[1024];
    const int CH = N1c / 1024;   // 42
    int tid = threadIdx.x;
    int base = tid * CH;
    int sum = 0;
    for (int j = 0; j < CH; ++j) sum += deg[base + j];
    s[tid] = sum;
    __syncthreads();
    for (int off = 1; off < 1024; off <<= 1) {
        int v = s[tid];
        int t = (tid >= off) ? s[tid - off] : 0;
        __syncthreads();
        s[tid] = v + t;
        __syncthreads();
    }
    int run = s[tid] - sum;      // exclusive prefix of this chunk
    for (int j = 0; j < CH; ++j) {
        int d = deg[base + j];
        offsets[base + j] = run;
        cursor[base + j]  = run;
        run += d;
    }
}

__global__ void fill_kernel(const int* __restrict__ src, const int* __restrict__ dst,
                            int* __restrict__ cursor, int* __restrict__ bucket, int nedges) {
    int e = blockIdx.x * blockDim.x + threadIdx.x;
    if (e < nedges) {
        int pos = atomicAdd(&cursor[dst[e]], 1);
        bucket[pos] = src[e];
    }
}

// ---- layer 0 aggregate: one wave per target row, 8 loads in flight ----
__global__ void __launch_bounds__(256)
aggr0_kernel(const float* __restrict__ x,
             const int* __restrict__ offsets, const int* __restrict__ deg,
             const int* __restrict__ bucket,
             float* __restrict__ aggr) {
    int i = blockIdx.x * 4 + (threadIdx.x >> 6);
    int lane = threadIdx.x & 63;
    if (i >= N1c) return;
    int off = offsets[i];
    int dg  = deg[i];

    float a0 = 0.f, a1 = 0.f, a2 = 0.f, a3 = 0.f;
    float a4 = 0.f, a5 = 0.f, a6 = 0.f, a7 = 0.f;

    for (int base = 0; base < dg; base += 64) {
        int m = dg - base; if (m > 64) m = 64;
        int sidx = (lane < m) ? bucket[off + base + lane] : 0;
        for (int t = 0; t < m; t += 8) {
            int s0 = __builtin_amdgcn_readlane(sidx, (t + 0) & 63);
            int s1 = __builtin_amdgcn_readlane(sidx, (t + 1) & 63);
            int s2 = __builtin_amdgcn_readlane(sidx, (t + 2) & 63);
            int s3 = __builtin_amdgcn_readlane(sidx, (t + 3) & 63);
            int s4 = __builtin_amdgcn_readlane(sidx, (t + 4) & 63);
            int s5 = __builtin_amdgcn_readlane(sidx, (t + 5) & 63);
            int s6 = __builtin_amdgcn_readlane(sidx, (t + 6) & 63);
            int s7 = __builtin_amdgcn_readlane(sidx, (t + 7) & 63);
            float v0 = x[(size_t)s0 * D + lane];
            float v1 = x[(size_t)s1 * D + lane];
            float v2 = x[(size_t)s2 * D + lane];
            float v3 = x[(size_t)s3 * D + lane];
            float v4 = x[(size_t)s4 * D + lane];
            float v5 = x[(size_t)s5 * D + lane];
            float v6 = x[(size_t)s6 * D + lane];
            float v7 = x[(size_t)s7 * D + lane];
            a0 += v0;                              // t+0 < m always
            a1 += (t + 1 < m) ? v1 : 0.f;
            a2 += (t + 2 < m) ? v2 : 0.f;
            a3 += (t + 3 < m) ? v3 : 0.f;
            a4 += (t + 4 < m) ? v4 : 0.f;
            a5 += (t + 5 < m) ? v5 : 0.f;
            a6 += (t + 6 < m) ? v6 : 0.f;
            a7 += (t + 7 < m) ? v7 : 0.f;
        }
    }
    float sum = ((a0 + a1) + (a2 + a3)) + ((a4 + a5) + (a6 + a7));
    float inv = 1.0f / fmaxf((float)dg, 1.0f);
    aggr[(size_t)i * D + lane] = sum * inv;
}

// ---- layer 0 dense: 4 rows per wave, w0 in LDS ----
__global__ void __launch_bounds__(256)
dense0_kernel(const float* __restrict__ x, const float* __restrict__ aggr,
              const float* __restrict__ w0, const float* __restrict__ b0,
              float* __restrict__ h) {
    __shared__ float wlds[2 * D * D];   // 8192 floats = 32 KB
    int tid = threadIdx.x;
    {   // vectorized stage of w0
        const float4* wsrc = (const float4*)w0;
        float4* wdst = (float4*)wlds;
#pragma unroll
        for (int t = 0; t < 8; ++t)
            wdst[t * 256 + tid] = wsrc[t * 256 + tid];
    }
    __syncthreads();

    int wv = tid >> 6, lane = tid & 63;
    int i0 = (blockIdx.x * 4 + wv) * 4;          // 4 rows per wave

    float x0 = x[(size_t)(i0 + 0) * D + lane];
    float x1 = x[(size_t)(i0 + 1) * D + lane];
    float x2 = x[(size_t)(i0 + 2) * D + lane];
    float x3 = x[(size_t)(i0 + 3) * D + lane];
    float g0 = aggr[(size_t)(i0 + 0) * D + lane];
    float g1 = aggr[(size_t)(i0 + 1) * D + lane];
    float g2 = aggr[(size_t)(i0 + 2) * D + lane];
    float g3 = aggr[(size_t)(i0 + 3) * D + lane];

    float bb = b0[lane];
    float o0 = bb, o1 = bb, o2 = bb, o3 = bb;

#pragma unroll 16
    for (int k = 0; k < D; ++k) {
        float ws = wlds[k * D + lane];
        float wa = wlds[(D + k) * D + lane];
        o0 += readlane_f(x0, k) * ws + readlane_f(g0, k) * wa;
        o1 += readlane_f(x1, k) * ws + readlane_f(g1, k) * wa;
        o2 += readlane_f(x2, k) * ws + readlane_f(g2, k) * wa;
        o3 += readlane_f(x3, k) * ws + readlane_f(g3, k) * wa;
    }
    h[(size_t)(i0 + 0) * D + lane] = fmaxf(o0, 0.f);
    h[(size_t)(i0 + 1) * D + lane] = fmaxf(o1, 0.f);
    h[(size_t)(i0 + 2) * D + lane] = fmaxf(o2, 0.f);
    h[(size_t)(i0 + 3) * D + lane] = fmaxf(o3, 0.f);
}

// ---- layer 1: small, atomic scatter + simple dense ----
__global__ void scatter_kernel(const float* __restrict__ feat,
                               const int* __restrict__ src,
                               const int* __restrict__ dst,
                               float* __restrict__ sums,
                               float* __restrict__ cnt,
                               int nedges) {
    long long tid = (long long)blockIdx.x * blockDim.x + threadIdx.x;
    int e = (int)(tid >> 6);
    int d = (int)(tid & 63);
    if (e >= nedges) return;
    int s = src[e];
    int t = dst[e];
    atomicAdd(&sums[(size_t)t * D + d], feat[(size_t)s * D + d]);
    if (d == 0) atomicAdd(&cnt[t], 1.0f);
}

__global__ void dense_kernel(const float* __restrict__ self_feat,
                             const float* __restrict__ sums,
                             const float* __restrict__ cnt,
                             const float* __restrict__ w,
                             const float* __restrict__ b,
                             float* __restrict__ out,
                             int nrows, int do_relu) {
    long long tid = (long long)blockIdx.x * blockDim.x + threadIdx.x;
    int i = (int)(tid >> 6);
    int j = (int)(tid & 63);
    if (i >= nrows) return;
    float inv = 1.0f / fmaxf(cnt[i], 1.0f);
    float acc = b[j];
    const float* xr = self_feat + (size_t)i * D;
    const float* sr = sums + (size_t)i * D;
#pragma unroll 8
    for (int k = 0; k < D; ++k)
        acc += xr[k] * w[k * D + j];
#pragma unroll 8
    for (int k = 0; k < D; ++k)
        acc += (sr[k] * inv) * w[(D + k) * D + j];
    if (do_relu) acc = fmaxf(acc, 0.0f);
    out[(size_t)i * D + j] = acc;
}

extern "C" void kernel_launch(void* const* d_in, const int* in_sizes, int n_in,
                              void* d_out, int out_size, void* d_ws, size_t ws_size,
                              hipStream_t stream) {
    const float* x   = (const float*)d_in[0];
    const float* w0  = (const float*)d_in[1];
    const float* b0  = (const float*)d_in[2];
    const float* w1  = (const float*)d_in[3];
    const float* b1  = (const float*)d_in[4];
    const int* es0   = (const int*)d_in[5];
    const int* ed0   = (const int*)d_in[6];
    const int* es1   = (const int*)d_in[7];
    const int* ed1   = (const int*)d_in[8];
    const int E0 = in_sizes[5];
    const int E1 = in_sizes[7];

    // Workspace layout. [deg | sum1 | cnt1] zeroed by one memset.
    int*   deg    = (int*)d_ws;                    // N1c
    float* sum1   = (float*)(deg + N1c);           // N2c*D
    float* cnt1   = sum1 + (size_t)N2c * D;        // N2c
    int*   offsets= (int*)(cnt1 + N2c);            // N1c
    int*   cursor = offsets + N1c;                 // N1c
    int*   bucket = cursor + N1c;                  // E0
    float* aggr   = (float*)(bucket + E0);         // N1c*D
    float* h      = aggr + (size_t)N1c * D;        // N1c*D

    size_t zero_bytes = ((size_t)N1c + (size_t)N2c * D + N2c) * sizeof(int);
    hipMemsetAsync(d_ws, 0, zero_bytes, stream);

    // CSR build for layer 0
    hist_kernel<<<(E0 + 255) / 256, 256, 0, stream>>>(ed0, deg, E0);
    scan_kernel<<<1, 1024, 0, stream>>>(deg, offsets, cursor);
    fill_kernel<<<(E0 + 255) / 256, 256, 0, stream>>>(es0, ed0, cursor, bucket, E0);

    // layer 0: aggregate then dense+relu
    aggr0_kernel<<<N1c / 4, 256, 0, stream>>>(x, offsets, deg, bucket, aggr);
    dense0_kernel<<<N1c / 16, 256, 0, stream>>>(x, aggr, w0, b0, h);

    // layer 1
    {
        long long threads = (long long)E1 * 64;
        int blocks = (int)((threads + 255) / 256);
        scatter_kernel<<<blocks, 256, 0, stream>>>(h, es1, ed1, sum1, cnt1, E1);
    }
    dense_kernel<<<(N2c * 64 + 255) / 256, 256, 0, stream>>>(h, sum1, cnt1, w1, b1,
                                                             (float*)d_out, N2c, 0);
}